// Round 7
// baseline (157.409 us; speedup 1.0000x reference)
//
#include <hip/hip_runtime.h>
#include <math.h>

#define B_ 64
#define S_ 512
#define N_ 24
#define H_ 768
#define C_ 6

// VALU-pipe cross-lane add via DPP (ctrl must be an immediate -> template).
// quad_perm(1,0,3,2)=0xB1 (xor1), quad_perm(2,3,0,1)=0x4E (xor2),
// row_half_mirror=0x141 (mirror within 8), row_mirror=0x140 (mirror within 16):
// after these 4 steps every lane holds its row-of-16 sum.
template <int CTRL>
__device__ __forceinline__ float dpp_add(float v) {
  int x = __builtin_amdgcn_update_dpp(0, __float_as_int(v), CTRL, 0xF, 0xF, true);
  return v + __int_as_float(x);
}
__device__ __forceinline__ float wave_sum(float v) {
  v = dpp_add<0xB1>(v);
  v = dpp_add<0x4E>(v);
  v = dpp_add<0x141>(v);
  v = dpp_add<0x140>(v);
  v += __shfl_xor(v, 16, 64);  // cross rows
  v += __shfl_xor(v, 32, 64);
  return v;  // full sum in all lanes
}

// Stage A: pure streaming projection Y[b,s,c] = sum_h X[b,s,h]*W[c,h].
// No LDS, no atomics, no ballots, no barriers, no boundary reads.
// 2048 blocks x 256 thr = 8192 waves x 4 tokens = 32768 tokens exactly.
__global__ __launch_bounds__(256, 4) void proj_kernel(
    const float* __restrict__ lhs, const float* __restrict__ W,
    float* __restrict__ Y) {
  const int tid = threadIdx.x;
  const int lane = tid & 63;
  const int gwave = (int)((blockIdx.x * 256 + tid) >> 6);
  const int t_base = gwave * 4;

  // W fragment: lane holds W[c][k*256 + lane*4 .. +3], k=0..2, c=0..5 (72 VGPRs)
  const float4* W4 = (const float4*)W;
  float4 w[3][C_];
#pragma unroll
  for (int k = 0; k < 3; ++k)
#pragma unroll
    for (int c = 0; c < C_; ++c)
      w[k][c] = W4[c * (H_ / 4) + k * 64 + lane];
#pragma unroll
  for (int k = 0; k < 3; ++k)
    asm volatile("" : "+v"(w[k][0].x), "+v"(w[k][0].y), "+v"(w[k][0].z), "+v"(w[k][0].w),
                       "+v"(w[k][1].x), "+v"(w[k][1].y), "+v"(w[k][1].z), "+v"(w[k][1].w),
                       "+v"(w[k][2].x), "+v"(w[k][2].y), "+v"(w[k][2].z), "+v"(w[k][2].w),
                       "+v"(w[k][3].x), "+v"(w[k][3].y), "+v"(w[k][3].z), "+v"(w[k][3].w),
                       "+v"(w[k][4].x), "+v"(w[k][4].y), "+v"(w[k][4].z), "+v"(w[k][4].w),
                       "+v"(w[k][5].x), "+v"(w[k][5].y), "+v"(w[k][5].z), "+v"(w[k][5].w));

  const float4* x4 = (const float4*)(lhs + (size_t)t_base * H_);

#pragma unroll
  for (int r = 0; r < 2; ++r) {
    // two tokens per round: 6 independent 1-KiB loads in flight
    float4 x0[3], x1[3];
#pragma unroll
    for (int k = 0; k < 3; ++k) x0[k] = x4[r * 384 + k * 64 + lane];
#pragma unroll
    for (int k = 0; k < 3; ++k) x1[k] = x4[r * 384 + 192 + k * 64 + lane];

#pragma unroll
    for (int tt = 0; tt < 2; ++tt) {
      const float4* xx = tt ? x1 : x0;
      float y[C_];
#pragma unroll
      for (int c = 0; c < C_; ++c) y[c] = 0.f;
#pragma unroll
      for (int k = 0; k < 3; ++k)
#pragma unroll
        for (int c = 0; c < C_; ++c)
          y[c] += xx[k].x * w[k][c].x + xx[k].y * w[k][c].y +
                  xx[k].z * w[k][c].z + xx[k].w * w[k][c].w;
      // cross-lane reduce on the VALU pipe (interleaved for ILP)
#pragma unroll
      for (int c = 0; c < C_; ++c) y[c] = wave_sum(y[c]);
      // lanes 0..5 store the 6 channels
      float out = y[0];
      out = (lane == 1) ? y[1] : out;
      out = (lane == 2) ? y[2] : out;
      out = (lane == 3) ? y[3] : out;
      out = (lane == 4) ? y[4] : out;
      out = (lane == 5) ? y[5] : out;
      const int t = t_base + r * 2 + tt;
      if (lane < C_) Y[(size_t)t * C_ + lane] = out;
    }
  }
}

// Stage B: one block per batch. Y[b] (512x6 = 12 KB) -> LDS, 144 threads each
// sum their (segment j, channel c), sigmoid + const override, store.
__global__ __launch_bounds__(256) void seg_finalize(
    const float* __restrict__ Y, const int* __restrict__ st,
    const float* __restrict__ bias, float* __restrict__ out) {
  __shared__ float ly[S_ * C_];  // 12 KB
  __shared__ int lst[N_];
  __shared__ float lb[C_];
  const int tid = threadIdx.x;
  const int b = blockIdx.x;

  const float4* Y4 = (const float4*)(Y + (size_t)b * S_ * C_);
  float4* ly4 = (float4*)ly;
#pragma unroll
  for (int i = 0; i < 3; ++i) ly4[i * 256 + tid] = Y4[i * 256 + tid];
  if (tid < N_) lst[tid] = st[b * N_ + tid];
  if (tid < C_) lb[tid] = bias[tid];
  __syncthreads();

  if (tid < N_ * C_) {
    const int j = tid / C_;
    const int c = tid % C_;
    const int end = lst[j];
    const int prev = (j == 0) ? -1 : lst[j - 1];
    float s = 0.f;
    for (int k = prev + 1; k <= end; ++k) s += ly[k * C_ + c];
    float logit = s / (float)(end - prev) + lb[c];
    float p = 1.0f / (1.0f + expf(-logit));
    if (end > 500) {
      float cl = (c < 3) ? 0.1f : (c == 3 ? 0.3f : (c == 4 ? 0.8f : 0.01f));
      float cm = (c < 3) ? 0.1f : (c == 3 ? 0.8f : (c == 4 ? 0.3f : 0.01f));
      p = (j == N_ - 1) ? cl : cm;
    }
    out[b * N_ * C_ + tid] = p;
  }
}

extern "C" void kernel_launch(void* const* d_in, const int* in_sizes, int n_in,
                              void* d_out, int out_size, void* d_ws, size_t ws_size,
                              hipStream_t stream) {
  const float* lhs  = (const float*)d_in[0];  // [B,S,H] fp32
  const int*   st   = (const int*)d_in[1];    // [B,N] int32
  const float* W    = (const float*)d_in[2];  // [C,H] fp32
  const float* bias = (const float*)d_in[3];  // [C] fp32
  float* Y = (float*)d_ws;                    // [B,S,C] fp32 (786 KB)

  proj_kernel<<<2048, 256, 0, stream>>>(lhs, W, Y);
  seg_finalize<<<B_, 256, 0, stream>>>(Y, st, bias, (float*)d_out);
}